// Round 2
// baseline (544.856 us; speedup 1.0000x reference)
//
#include <hip/hip_runtime.h>
#include <stdint.h>

typedef unsigned short u16;
typedef __attribute__((ext_vector_type(8))) short bf16x8;   // 8 bf16 = 4 VGPRs (MFMA A/B frag)
typedef __attribute__((ext_vector_type(4))) float f32x4;    // MFMA C/D frag

__device__ __forceinline__ u16 f2b(float f) {
  unsigned u = __float_as_uint(f);
  unsigned r = (u + 0x7fffu + ((u >> 16) & 1u)) >> 16;  // RNE
  return (u16)r;
}
__device__ __forceinline__ float b2f(u16 s) { return __uint_as_float(((unsigned)s) << 16); }

// async global->LDS, 16B per lane; LDS dest = wave-uniform base + lane*16
__device__ __forceinline__ void async16(const void* g, void* l) {
  __builtin_amdgcn_global_load_lds((const __attribute__((address_space(1))) unsigned int*)g,
                                   (__attribute__((address_space(3))) unsigned int*)l, 16, 0, 0);
}

// ---------------- small prep kernels ----------------

__global__ void cast_bf16(const float* __restrict__ src, u16* __restrict__ dst, int n4) {
  int i = blockIdx.x * 256 + threadIdx.x;
  if (i >= n4) return;
  const float4 v = ((const float4*)src)[i];
  uint2 o;
  o.x = (unsigned)f2b(v.x) | ((unsigned)f2b(v.y) << 16);
  o.y = (unsigned)f2b(v.z) | ((unsigned)f2b(v.w) << 16);
  ((uint2*)dst)[i] = o;
}

// w_dwc[o][i][t] (fp32, t=dz*9+dy*3+dx) -> Wc[o][t][i] bf16  (k = t*256+i)
__global__ void pack_wc(const float* __restrict__ w, u16* __restrict__ Wc) {
  int idx = blockIdx.x * 256 + threadIdx.x;           // 256*27*256 = 1769472
  int o = idx / 6912;
  int rem = idx - o * 6912;
  int tp = rem >> 8, i = rem & 255;
  Wc[idx] = f2b(w[(o * 256 + i) * 27 + tp]);
}

// agent pooling, faithful to torch raw-reshape head interleave; scale folded in
__global__ void pool_A(const u16* __restrict__ QKV, u16* __restrict__ Abf) {
  int a = blockIdx.x;                      // 64 agents
  int t = threadIdx.x, hp = t >> 5, dp = t & 31;
  int p1 = a >> 4, p2 = (a >> 2) & 3, p3 = a & 3;
  float s = 0.f;
  for (int u = 0; u < 512; ++u) {
    int f1 = p1 * 8 + (u >> 6);
    int f2 = p2 * 8 + ((u >> 3) & 7);
    int f3 = p3 * 8 + (u & 7);
    int vox = f1 * 1024 + f2 * 32 + f3;
    int n  = ((vox & 4095) << 3) + hp;
    int cq = ((vox >> 12) << 5) + dp;
    s += b2f(QKV[n * 768 + cq]);           // Q region
  }
  Abf[(hp * 64 + a) * 32 + dp] = f2b(s * (0.17677669529663687f / 512.0f));
}

// V (QKV cols 512..768) -> padded 34^3 channel-last volume (halo zeroed)
__global__ void pad_v(const u16* __restrict__ QKV, u16* __restrict__ v5) {
  int idx = blockIdx.x * 256 + threadIdx.x;   // 39304*32 = 1257728
  int c8 = idx & 31, vox = idx >> 5;
  int z = vox / 1156, r2 = vox - z * 1156, y = r2 / 34, x = r2 - y * 34;
  bf16x8 val = {0, 0, 0, 0, 0, 0, 0, 0};
  if (z >= 1 && z <= 32 && y >= 1 && y <= 32 && x >= 1 && x <= 32) {
    int n = (z - 1) * 1024 + (y - 1) * 32 + (x - 1);
    val = *(const bf16x8*)(QKV + n * 768 + 512 + c8 * 8);
  }
  *(bf16x8*)(v5 + vox * 256 + c8 * 8) = val;
}

__global__ void s1_norm(const float* __restrict__ avac, const float* __restrict__ rsum,
                        u16* __restrict__ avt) {
  int idx = blockIdx.x * 256 + threadIdx.x;   // 16384
  int h = idx >> 11, rem = idx & 2047, a = rem >> 5, d = rem & 31;
  avt[(h * 32 + d) * 64 + a] = f2b(avac[idx] / rsum[h * 64 + a]);  // transposed for s2 B-frags
}

// ---------------- m97-style bf16 NT-GEMM pieces (conflict-free LDS layout) ----------------
// LDS tile layout: per 16-row group g: [kchunk(4)][row(16)][elem(8)] — staged so lane i
// writes bytes [16i,16i+16), and the MFMA frag read (row=c, kchunk=q) is exactly lane-linear
// (lane q*16+c reads offset (q*16+c)*16) — sequential => zero bank conflicts.

// stage 128x32 tile (8 groups); wave wv stages groups wv*2, wv*2+1
__device__ __forceinline__ void stage_tile(const u16* src, int row0, int ld, int k0,
                                           short* dst, int tid) {
  int wv = tid >> 6, lane = tid & 63;
#pragma unroll
  for (int j = 0; j < 2; ++j) {
    int g = wv * 2 + j;
    async16(src + (row0 + g * 16 + (lane & 15)) * ld + k0 + (lane >> 4) * 8, dst + g * 512);
  }
}

__device__ __forceinline__ void mfma_tile(const short* As, const short* Bs, int wm, int wn,
                                          int lane, f32x4 acc[4][4]) {
  const int q = lane >> 4, c = lane & 15;
  const int fo = q * 128 + c * 8;
  bf16x8 a[4], b[4];
#pragma unroll
  for (int mt = 0; mt < 4; ++mt) a[mt] = *(const bf16x8*)&As[(wm * 4 + mt) * 512 + fo];
#pragma unroll
  for (int nt = 0; nt < 4; ++nt) b[nt] = *(const bf16x8*)&Bs[(wn * 4 + nt) * 512 + fo];
#pragma unroll
  for (int mt = 0; mt < 4; ++mt)
#pragma unroll
    for (int nt = 0; nt < 4; ++nt)
      acc[mt][nt] = __builtin_amdgcn_mfma_f32_16x16x32_bf16(a[mt], b[nt], acc[mt][nt], 0, 0, 0);
}

// QKV = Xb @ Wq^T + b, bf16 out (32768 x 768)
__global__ __launch_bounds__(256) void gemm_qkv(const u16* __restrict__ Xb,
                                                const u16* __restrict__ Wq,
                                                const float* __restrict__ bias,
                                                u16* __restrict__ QKV) {
  const int m0 = blockIdx.x * 128, n0 = blockIdx.y * 128;
  const int tid = threadIdx.x, lane = tid & 63, wv = tid >> 6;
  const int wm = wv >> 1, wn = wv & 1, q = lane >> 4, c = lane & 15;
  __shared__ short As[4096], Bs[4096];
  f32x4 acc[4][4] = {};
  for (int kb = 0; kb < 256; kb += 32) {
    stage_tile(Xb, m0, 256, kb, As, tid);
    stage_tile(Wq, n0, 256, kb, Bs, tid);
    __syncthreads();
    mfma_tile(As, Bs, wm, wn, lane, acc);
    __syncthreads();
  }
#pragma unroll
  for (int nt = 0; nt < 4; ++nt) {
    int col = n0 + wn * 64 + nt * 16 + c;
    float bv = bias[col];
#pragma unroll
    for (int mt = 0; mt < 4; ++mt) {
      int row = m0 + wm * 64 + mt * 16 + q * 4;
#pragma unroll
      for (int r = 0; r < 4; ++r) QKV[(row + r) * 768 + col] = f2b(acc[mt][nt][r] + bv);
    }
  }
}

// implicit-GEMM full 3D conv: M=32768 vox, N=256 oc, K=27*256; 128x64 tiles for occupancy
__global__ __launch_bounds__(256) void gemm_conv(const u16* __restrict__ v5,
                                                 const u16* __restrict__ Wc,
                                                 const float* __restrict__ bias,
                                                 u16* __restrict__ Xp) {
  const int m0 = blockIdx.x * 128, n0 = blockIdx.y * 64;
  const int tid = threadIdx.x, lane = tid & 63, wv = tid >> 6;
  const int wm = wv >> 1, wn = wv & 1, q = lane >> 4, c = lane & 15;
  __shared__ short As[4096], Bs[2048];
  int pb[2];
#pragma unroll
  for (int j = 0; j < 2; ++j) {
    int n = m0 + (wv * 2 + j) * 16 + (lane & 15);
    int z = n >> 10, y = (n >> 5) & 31, x = n & 31;
    pb[j] = z * 1156 + y * 34 + x;         // padded-volume base (tap 0,0,0)
  }
  const int kc8 = (lane >> 4) * 8;
  const u16* browB = Wc + (n0 + wv * 16 + (lane & 15)) * 6912 + kc8;
  short* dstA0 = As + (wv * 2) * 512;
  short* dstA1 = As + (wv * 2 + 1) * 512;
  short* dstB  = Bs + wv * 512;
  f32x4 acc[4][2] = {};
  for (int tap = 0; tap < 27; ++tap) {
    int dz = tap / 9, rt = tap - dz * 9, dy = rt / 3, dx = rt - dy * 3;
    int toff = dz * 1156 + dy * 34 + dx;
    const u16* a0 = v5 + ((pb[0] + toff) << 8) + kc8;
    const u16* a1 = v5 + ((pb[1] + toff) << 8) + kc8;
    const u16* bb = browB + tap * 256;
#pragma unroll 1
    for (int i8 = 0; i8 < 8; ++i8) {
      async16(a0 + i8 * 32, dstA0);
      async16(a1 + i8 * 32, dstA1);
      async16(bb + i8 * 32, dstB);
      __syncthreads();
      const int fo = q * 128 + c * 8;
      bf16x8 a[4], b[2];
#pragma unroll
      for (int mt = 0; mt < 4; ++mt) a[mt] = *(const bf16x8*)&As[(wm * 4 + mt) * 512 + fo];
#pragma unroll
      for (int nt = 0; nt < 2; ++nt) b[nt] = *(const bf16x8*)&Bs[(wn * 2 + nt) * 512 + fo];
#pragma unroll
      for (int mt = 0; mt < 4; ++mt)
#pragma unroll
        for (int nt = 0; nt < 2; ++nt)
          acc[mt][nt] = __builtin_amdgcn_mfma_f32_16x16x32_bf16(a[mt], b[nt], acc[mt][nt], 0, 0, 0);
      __syncthreads();
    }
  }
#pragma unroll
  for (int nt = 0; nt < 2; ++nt) {
    int col = n0 + wn * 32 + nt * 16 + c;
    float bv = bias[col];
#pragma unroll
    for (int mt = 0; mt < 4; ++mt) {
      int row = m0 + wm * 64 + mt * 16 + q * 4;
#pragma unroll
      for (int r = 0; r < 4; ++r) Xp[(row + r) * 256 + col] = f2b(acc[mt][nt][r] + bv);
    }
  }
}

// out = Xp @ Wp^T + b_proj, fp32 out (32768 x 256)
__global__ __launch_bounds__(256) void gemm_proj(const u16* __restrict__ Xp,
                                                 const u16* __restrict__ Wp,
                                                 const float* __restrict__ bias,
                                                 float* __restrict__ out) {
  const int m0 = blockIdx.x * 128, n0 = blockIdx.y * 128;
  const int tid = threadIdx.x, lane = tid & 63, wv = tid >> 6;
  const int wm = wv >> 1, wn = wv & 1, q = lane >> 4, c = lane & 15;
  __shared__ short As[4096], Bs[4096];
  f32x4 acc[4][4] = {};
  for (int kb = 0; kb < 256; kb += 32) {
    stage_tile(Xp, m0, 256, kb, As, tid);
    stage_tile(Wp, n0, 256, kb, Bs, tid);
    __syncthreads();
    mfma_tile(As, Bs, wm, wn, lane, acc);
    __syncthreads();
  }
#pragma unroll
  for (int nt = 0; nt < 4; ++nt) {
    int col = n0 + wn * 64 + nt * 16 + c;
    float bv = bias[col];
#pragma unroll
    for (int mt = 0; mt < 4; ++mt) {
      int row = m0 + wm * 64 + mt * 16 + q * 4;
#pragma unroll
      for (int r = 0; r < 4; ++r) out[(row + r) * 256 + col] = acc[mt][nt][r] + bv;
    }
  }
}

// ---------------- stage-1: agents attend keys, aggregate V (unnormalized + atomics) ----------
// grid (128 chunks of 256 tokens, 8 heads). Scores tiny (|s|<~1) -> exp without max-sub.
__global__ __launch_bounds__(256) void s1_attn(const u16* __restrict__ QKV,
                                               const u16* __restrict__ Abf,
                                               float* __restrict__ avac,
                                               float* __restrict__ rsum) {
  const int h = blockIdx.y, n0 = blockIdx.x * 256;
  const int tid = threadIdx.x, lane = tid & 63, wv = tid >> 6;
  const int q = lane >> 4, c = lane & 15;
  extern __shared__ char smem[];
  u16* E  = (u16*)smem;            // [64 agents][264] bf16 (pitch-padded)
  u16* VT = (u16*)(smem + 33792);  // [32 d][264] bf16
  float* RED = (float*)smem;       // overlay after E consumed: [4 waves][2048]

  { // stage V chunk transposed: VT[d][tok_local]
    const u16* vrow = QKV + (n0 + tid) * 768 + 512 + h * 32;
#pragma unroll
    for (int d8 = 0; d8 < 4; ++d8) {
      bf16x8 v = *(const bf16x8*)(vrow + d8 * 8);
#pragma unroll
      for (int e = 0; e < 8; ++e) VT[(d8 * 8 + e) * 264 + tid] = (u16)v[e];
    }
  }
  { // QK^T (M=64 agents, N=64 tokens per wave, K=32) + exp -> E
    bf16x8 af[4], bf[4];
#pragma unroll
    for (int mt = 0; mt < 4; ++mt)
      af[mt] = *(const bf16x8*)(Abf + h * 2048 + (mt * 16 + c) * 32 + q * 8);
#pragma unroll
    for (int nt = 0; nt < 4; ++nt)
      bf[nt] = *(const bf16x8*)(QKV + (n0 + wv * 64 + nt * 16 + c) * 768 + 256 + h * 32 + q * 8);
#pragma unroll
    for (int mt = 0; mt < 4; ++mt)
#pragma unroll
      for (int nt = 0; nt < 4; ++nt) {
        f32x4 s = {0.f, 0.f, 0.f, 0.f};
        s = __builtin_amdgcn_mfma_f32_16x16x32_bf16(af[mt], bf[nt], s, 0, 0, 0);
#pragma unroll
        for (int r = 0; r < 4; ++r) {
          int a = mt * 16 + q * 4 + r, nl = wv * 64 + nt * 16 + c;
          E[a * 264 + nl] = f2b(__expf(s[r]));
        }
      }
  }
  __syncthreads();
  { // row sums of E (denominator partials)
    int a = tid >> 2, seg = tid & 3;
    float sum = 0.f;
    for (int i = 0; i < 64; ++i) sum += b2f(E[a * 264 + seg * 64 + i]);
    sum += __shfl_xor(sum, 1);
    sum += __shfl_xor(sum, 2);
    if (seg == 0) atomicAdd(&rsum[h * 64 + a], sum);
  }
  // PV: each wave reduces its own 64-token K-slab (M=64 agents, N=32 d)
  f32x4 pv[4][2] = {};
#pragma unroll
  for (int ks = 0; ks < 2; ++ks) {
    bf16x8 ap[4], bp[2];
#pragma unroll
    for (int mt = 0; mt < 4; ++mt)
      ap[mt] = *(const bf16x8*)&E[(mt * 16 + c) * 264 + wv * 64 + ks * 32 + q * 8];
#pragma unroll
    for (int nt = 0; nt < 2; ++nt)
      bp[nt] = *(const bf16x8*)&VT[(nt * 16 + c) * 264 + wv * 64 + ks * 32 + q * 8];
#pragma unroll
    for (int mt = 0; mt < 4; ++mt)
#pragma unroll
      for (int nt = 0; nt < 2; ++nt)
        pv[mt][nt] = __builtin_amdgcn_mfma_f32_16x16x32_bf16(ap[mt], bp[nt], pv[mt][nt], 0, 0, 0);
  }
  __syncthreads();            // all E/VT reads done; reuse smem as RED
#pragma unroll
  for (int mt = 0; mt < 4; ++mt)
#pragma unroll
    for (int nt = 0; nt < 2; ++nt)
#pragma unroll
      for (int r = 0; r < 4; ++r)
        RED[wv * 2048 + (mt * 16 + q * 4 + r) * 32 + nt * 16 + c] = pv[mt][nt][r];
  __syncthreads();
  for (int idx = tid; idx < 2048; idx += 256) {
    float t = RED[idx] + RED[2048 + idx] + RED[4096 + idx] + RED[6144 + idx];
    atomicAdd(&avac[h * 2048 + idx], t);
  }
}

// ---------------- stage-2: queries attend agents; scatter-add into Xp ----------------
__global__ __launch_bounds__(256) void s2_attn(const u16* __restrict__ QKV,
                                               const u16* __restrict__ Abf,
                                               const u16* __restrict__ avt,
                                               u16* __restrict__ Xp) {
  const int h = blockIdx.y, n0 = blockIdx.x * 256;
  const int tid = threadIdx.x, lane = tid & 63, wv = tid >> 6;
  const int q = lane >> 4, c = lane & 15;
  extern __shared__ char smem[];
  u16* P = (u16*)smem;      // [256 tok][72] bf16
  float* O = (float*)smem;  // overlay later: [32 d][258] f32

  f32x4 s[4][4];
  { // QK^T: M=64 tokens/wave, N=64 agents, K=32
    bf16x8 af[4], bf[4];
#pragma unroll
    for (int mt = 0; mt < 4; ++mt)
      af[mt] = *(const bf16x8*)(QKV + (n0 + wv * 64 + mt * 16 + c) * 768 + h * 32 + q * 8);
#pragma unroll
    for (int nt = 0; nt < 4; ++nt)
      bf[nt] = *(const bf16x8*)(Abf + h * 2048 + (nt * 16 + c) * 32 + q * 8);
#pragma unroll
    for (int mt = 0; mt < 4; ++mt)
#pragma unroll
      for (int nt = 0; nt < 4; ++nt) {
        f32x4 z = {0.f, 0.f, 0.f, 0.f};
        s[mt][nt] = __builtin_amdgcn_mfma_f32_16x16x32_bf16(af[mt], bf[nt], z, 0, 0, 0);
      }
  }
  // softmax across 64 agents per token row: 4 reg-values + shfl over 16-lane col group
#pragma unroll
  for (int mt = 0; mt < 4; ++mt)
#pragma unroll
    for (int r = 0; r < 4; ++r) {
      float v0 = s[mt][0][r], v1 = s[mt][1][r], v2 = s[mt][2][r], v3 = s[mt][3][r];
      float mx = fmaxf(fmaxf(v0, v1), fmaxf(v2, v3));
      mx = fmaxf(mx, __shfl_xor(mx, 1));
      mx = fmaxf(mx, __shfl_xor(mx, 2));
      mx = fmaxf(mx, __shfl_xor(mx, 4));
      mx = fmaxf(mx, __shfl_xor(mx, 8));
      float e0 = __expf(v0 - mx), e1 = __expf(v1 - mx), e2 = __expf(v2 - mx), e3 = __expf(v3 - mx);
      float sm = e0 + e1 + e2 + e3;
      sm += __shfl_xor(sm, 1);
      sm += __shfl_xor(sm, 2);
      sm += __shfl_xor(sm, 4);
      sm += __shfl_xor(sm, 8);
      float inv = 1.0f / sm;
      int tok = wv * 64 + mt * 16 + q * 4 + r;
      P[tok * 72 +      c] = f2b(e0 * inv);
      P[tok * 72 + 16 + c] = f2b(e1 * inv);
      P[tok * 72 + 32 + c] = f2b(e2 * inv);
      P[tok * 72 + 48 + c] = f2b(e3 * inv);
    }
  __syncthreads();
  // PV: O = P(64x64) @ agent_v(64x32); avt is [h][d][a] (K=a contiguous)
  f32x4 o[4][2] = {};
#pragma unroll
  for (int ks = 0; ks < 2; ++ks) {
    bf16x8 ap[4], bv[2];
#pragma unroll
    for (int mt = 0; mt < 4; ++mt)
      ap[mt] = *(const bf16x8*)&P[(wv * 64 + mt * 16 + c) * 72 + ks * 32 + q * 8];
#pragma unroll
    for (int nt = 0; nt < 2; ++nt)
      bv[nt] = *(const bf16x8*)(avt + h * 2048 + (nt * 16 + c) * 64 + ks * 32 + q * 8);
#pragma unroll
    for (int mt = 0; mt < 4; ++mt)
#pragma unroll
      for (int nt = 0; nt < 2; ++nt)
        o[mt][nt] = __builtin_amdgcn_mfma_f32_16x16x32_bf16(ap[mt], bv[nt], o[mt][nt], 0, 0, 0);
  }
  __syncthreads();  // P reads done; reuse smem as O
#pragma unroll
  for (int mt = 0; mt < 4; ++mt)
#pragma unroll
    for (int nt = 0; nt < 2; ++nt)
#pragma unroll
      for (int r = 0; r < 4; ++r)
        O[(nt * 16 + c) * 258 + wv * 64 + mt * 16 + q * 4 + r] = o[mt][nt][r];
  __syncthreads();
  // coalesced RMW: flat offset (h*32+d)*32768 + n == row-major (n',c') of the torch reshape
  for (int d = 0; d < 32; ++d) {
    int addr = (h * 32 + d) * 32768 + n0 + tid;
    Xp[addr] = f2b(b2f(Xp[addr]) + O[d * 258 + tid]);
  }
}

// ---------------- launch ----------------

extern "C" void kernel_launch(void* const* d_in, const int* in_sizes, int n_in,
                              void* d_out, int out_size, void* d_ws, size_t ws_size,
                              hipStream_t stream) {
  const float* x      = (const float*)d_in[0];
  const float* w_qkv  = (const float*)d_in[1];
  const float* b_qkv  = (const float*)d_in[2];
  const float* w_proj = (const float*)d_in[3];
  const float* b_proj = (const float*)d_in[4];
  const float* w_dwc  = (const float*)d_in[5];
  const float* b_dwc  = (const float*)d_in[6];
  float* out = (float*)d_out;
  char* ws = (char*)d_ws;

  u16* Xb   = (u16*)(ws);              // 16 MB; reused as Xp after QKV GEMM
  u16* QKV  = (u16*)(ws + 16777216);   // 48 MB bf16 (32768 x 768)
  u16* V5   = (u16*)(ws + 67108864);   // 20.1 MB padded volume
  u16* Wc   = (u16*)(ws + 87232512);   // 3.5 MB conv weights [o][t][i]
  u16* Wqb  = (u16*)(ws + 90771456);
  u16* Wpb  = (u16*)(ws + 91164672);
  u16* Abf  = (u16*)(ws + 91295744);   // agents [h][a][d], scale folded
  u16* AVT  = (u16*)(ws + 91328512);   // agent_v^T [h][d][a]
  float* AVAC = (float*)(ws + 91361280);
  float* RSUM = (float*)(ws + 91426816);
  u16* Xp = Xb;

  hipMemsetAsync(AVAC, 0, 65536 + 2048, stream);
  cast_bf16<<<8192, 256, 0, stream>>>(x, Xb, 2097152);
  cast_bf16<<<192, 256, 0, stream>>>(w_qkv, Wqb, 49152);
  cast_bf16<<<64, 256, 0, stream>>>(w_proj, Wpb, 16384);
  pack_wc<<<6912, 256, 0, stream>>>(w_dwc, Wc);
  gemm_qkv<<<dim3(256, 6), 256, 0, stream>>>(Xb, Wqb, b_qkv, QKV);
  pool_A<<<64, 256, 0, stream>>>(QKV, Abf);
  pad_v<<<4913, 256, 0, stream>>>(QKV, V5);
  s1_attn<<<dim3(128, 8), 256, 50688, stream>>>(QKV, Abf, AVAC, RSUM);
  s1_norm<<<64, 256, 0, stream>>>(AVAC, RSUM, AVT);
  gemm_conv<<<dim3(256, 4), 256, 0, stream>>>(V5, Wc, b_dwc, Xp);
  s2_attn<<<dim3(128, 8), 256, 36864, stream>>>(QKV, Abf, AVT, Xp);
  gemm_proj<<<dim3(256, 2), 256, 0, stream>>>(Xp, Wpb, b_proj, out);
}

// Round 3
// 407.531 us; speedup vs baseline: 1.3370x; 1.3370x over previous
//
#include <hip/hip_runtime.h>
#include <stdint.h>

typedef unsigned short u16;
typedef __attribute__((ext_vector_type(8))) short bf16x8;   // 8 bf16 = 4 VGPRs (MFMA A/B frag)
typedef __attribute__((ext_vector_type(4))) float f32x4;    // MFMA C/D frag

__device__ __forceinline__ u16 f2b(float f) {
  unsigned u = __float_as_uint(f);
  unsigned r = (u + 0x7fffu + ((u >> 16) & 1u)) >> 16;  // RNE
  return (u16)r;
}
__device__ __forceinline__ float b2f(u16 s) { return __uint_as_float(((unsigned)s) << 16); }

// async global->LDS, 16B per lane; LDS dest = wave-uniform base + lane*16
__device__ __forceinline__ void async16(const void* g, void* l) {
  __builtin_amdgcn_global_load_lds((const __attribute__((address_space(1))) unsigned int*)g,
                                   (__attribute__((address_space(3))) unsigned int*)l, 16, 0, 0);
}

// ---------------- small prep kernels ----------------

__global__ void cast_bf16(const float* __restrict__ src, u16* __restrict__ dst, int n4) {
  int i = blockIdx.x * 256 + threadIdx.x;
  if (i >= n4) return;
  const float4 v = ((const float4*)src)[i];
  uint2 o;
  o.x = (unsigned)f2b(v.x) | ((unsigned)f2b(v.y) << 16);
  o.y = (unsigned)f2b(v.z) | ((unsigned)f2b(v.w) << 16);
  ((uint2*)dst)[i] = o;
}

// w_dwc[o][i][t] (fp32) -> Wc[o][t][i] bf16, via LDS transpose (coalesced both sides)
__global__ void pack_wc(const float* __restrict__ w, u16* __restrict__ Wc) {
  int o = blockIdx.x;
  __shared__ u16 lds[6912];
  for (int t = threadIdx.x; t < 6912; t += 256) lds[t] = f2b(w[o * 6912 + t]);  // t = i*27+tp
  __syncthreads();
  for (int idx = threadIdx.x; idx < 6912; idx += 256) {
    int tp = idx >> 8, i = idx & 255;
    Wc[o * 6912 + idx] = lds[i * 27 + tp];
  }
}

// agent pooling partials: block (a, slab s of 64 source voxels) -> atomicAdd fp32
__global__ void pool_A(const u16* __restrict__ QKV, float* __restrict__ Apre) {
  int a = blockIdx.x >> 3, s = blockIdx.x & 7;
  int t = threadIdx.x, hp = t >> 5, dp = t & 31;
  int p1 = a >> 4, p2 = (a >> 2) & 3, p3 = a & 3;
  float sum = 0.f;
  for (int ui = 0; ui < 64; ++ui) {
    int u = s * 64 + ui;
    int f1 = p1 * 8 + (u >> 6);
    int f2 = p2 * 8 + ((u >> 3) & 7);
    int f3 = p3 * 8 + (u & 7);
    int vox = f1 * 1024 + f2 * 32 + f3;
    int n  = ((vox & 4095) << 3) + hp;
    int cq = ((vox >> 12) << 5) + dp;
    sum += b2f(QKV[n * 768 + cq]);           // Q region
  }
  atomicAdd(&Apre[(hp * 64 + a) * 32 + dp], sum);
}

__global__ void pool_fin(const float* __restrict__ Apre, u16* __restrict__ Abf) {
  int idx = blockIdx.x * 256 + threadIdx.x;  // 16384
  Abf[idx] = f2b(Apre[idx] * (0.17677669529663687f / 512.0f));
}

// V (QKV cols 512..768) -> padded 34^3 channel-last volume (halo zeroed)
__global__ void pad_v(const u16* __restrict__ QKV, u16* __restrict__ v5) {
  int idx = blockIdx.x * 256 + threadIdx.x;   // 39304*32 = 1257728
  int c8 = idx & 31, vox = idx >> 5;
  int z = vox / 1156, r2 = vox - z * 1156, y = r2 / 34, x = r2 - y * 34;
  bf16x8 val = {0, 0, 0, 0, 0, 0, 0, 0};
  if (z >= 1 && z <= 32 && y >= 1 && y <= 32 && x >= 1 && x <= 32) {
    int n = (z - 1) * 1024 + (y - 1) * 32 + (x - 1);
    val = *(const bf16x8*)(QKV + n * 768 + 512 + c8 * 8);
  }
  *(bf16x8*)(v5 + vox * 256 + c8 * 8) = val;
}

__global__ void s1_norm(const float* __restrict__ avac, const float* __restrict__ rsum,
                        u16* __restrict__ avt) {
  int idx = blockIdx.x * 256 + threadIdx.x;   // 16384
  int h = idx >> 11, rem = idx & 2047, a = rem >> 5, d = rem & 31;
  avt[(h * 32 + d) * 64 + a] = f2b(avac[idx] / rsum[h * 64 + a]);  // transposed for s2 B-frags
}

// ---------------- bf16 NT-GEMM pieces: BK=64 (two 32-K panels), conflict-free LDS --------
// Panel p in {0,1}, group g in [0,8): LDS addr = p*4096 + g*512 + kchunk*128 + row*8
// staged lane-linear (lane = kchunk*16 + row), so both the async16 write and the MFMA
// frag read (lane q*16+c reads offset (q*16+c)*8 shorts) are sequential: zero conflicts.

__device__ __forceinline__ void stage64(const u16* src, int row0, int ld, int k0,
                                        short* dst, int tid) {
  int wv = tid >> 6, lane = tid & 63;
  int r15 = lane & 15, kc8 = (lane >> 4) * 8;
#pragma unroll
  for (int j = 0; j < 4; ++j) {
    int p = j & 1, g = wv * 2 + (j >> 1);
    async16(src + (row0 + g * 16 + r15) * ld + k0 + p * 32 + kc8, dst + p * 4096 + g * 512);
  }
}

__device__ __forceinline__ void mfma64(const short* As, const short* Bs, int wm, int wn,
                                       int lane, f32x4 acc[4][4]) {
  const int q = lane >> 4, c = lane & 15;
  const int fo = q * 128 + c * 8;
#pragma unroll
  for (int p = 0; p < 2; ++p) {
    bf16x8 a[4], b[4];
#pragma unroll
    for (int mt = 0; mt < 4; ++mt) a[mt] = *(const bf16x8*)&As[p * 4096 + (wm * 4 + mt) * 512 + fo];
#pragma unroll
    for (int nt = 0; nt < 4; ++nt) b[nt] = *(const bf16x8*)&Bs[p * 4096 + (wn * 4 + nt) * 512 + fo];
#pragma unroll
    for (int mt = 0; mt < 4; ++mt)
#pragma unroll
      for (int nt = 0; nt < 4; ++nt)
        acc[mt][nt] = __builtin_amdgcn_mfma_f32_16x16x32_bf16(a[mt], b[nt], acc[mt][nt], 0, 0, 0);
  }
}

// QKV = Xb @ Wq^T + b, bf16 out (32768 x 768)
__global__ __launch_bounds__(256) void gemm_qkv(const u16* __restrict__ Xb,
                                                const u16* __restrict__ Wq,
                                                const float* __restrict__ bias,
                                                u16* __restrict__ QKV) {
  const int m0 = blockIdx.x * 128, n0 = blockIdx.y * 128;
  const int tid = threadIdx.x, lane = tid & 63, wv = tid >> 6;
  const int wm = wv >> 1, wn = wv & 1, q = lane >> 4, c = lane & 15;
  __shared__ short As[8192], Bs[8192];
  f32x4 acc[4][4] = {};
  for (int kb = 0; kb < 256; kb += 64) {
    stage64(Xb, m0, 256, kb, As, tid);
    stage64(Wq, n0, 256, kb, Bs, tid);
    __syncthreads();
    mfma64(As, Bs, wm, wn, lane, acc);
    __syncthreads();
  }
#pragma unroll
  for (int nt = 0; nt < 4; ++nt) {
    int col = n0 + wn * 64 + nt * 16 + c;
    float bv = bias[col];
#pragma unroll
    for (int mt = 0; mt < 4; ++mt) {
      int row = m0 + wm * 64 + mt * 16 + q * 4;
#pragma unroll
      for (int r = 0; r < 4; ++r) QKV[(row + r) * 768 + col] = f2b(acc[mt][nt][r] + bv);
    }
  }
}

// implicit-GEMM 3D conv: M=32768 vox, N=256 oc, K=27*256. 128x128 tile, BK=64.
// 1D grid 512, XCD swizzle: n_half = bid&1 (each XCD L2 caches one 1.77MB B-half).
__global__ __launch_bounds__(256) void gemm_conv(const u16* __restrict__ v5,
                                                 const u16* __restrict__ Wc,
                                                 const float* __restrict__ bias,
                                                 u16* __restrict__ Xp) {
  const int bid = blockIdx.x;
  const int m0 = (bid >> 1) * 128, n0 = (bid & 1) * 128;
  const int tid = threadIdx.x, lane = tid & 63, wv = tid >> 6;
  const int wm = wv >> 1, wn = wv & 1, q = lane >> 4, c = lane & 15;
  const int r15 = lane & 15, kc8 = (lane >> 4) * 8;
  __shared__ short As[8192], Bs[8192];
  int pb[2];
  const u16* bbase[2];
#pragma unroll
  for (int jj = 0; jj < 2; ++jj) {
    int g = wv * 2 + jj;
    int n = m0 + g * 16 + r15;
    int z = n >> 10, y = (n >> 5) & 31, x = n & 31;
    pb[jj] = z * 1156 + y * 34 + x;        // padded-volume base (tap 0,0,0)
    bbase[jj] = Wc + (n0 + g * 16 + r15) * 6912 + kc8;
  }
  f32x4 acc[4][4] = {};
  for (int kb = 0; kb < 108; ++kb) {
    int tap = kb >> 2, i0 = (kb & 3) * 64;
    int dz = tap / 9, rt = tap - dz * 9, dy = rt / 3, dx = rt - dy * 3;
    int toff = dz * 1156 + dy * 34 + dx;
#pragma unroll
    for (int j = 0; j < 4; ++j) {
      int p = j & 1, jj = j >> 1, g = wv * 2 + jj;
      async16(v5 + ((pb[jj] + toff) << 8) + i0 + p * 32 + kc8, As + p * 4096 + g * 512);
      async16(bbase[jj] + tap * 256 + i0 + p * 32, Bs + p * 4096 + g * 512);
    }
    __syncthreads();
    mfma64(As, Bs, wm, wn, lane, acc);
    __syncthreads();
  }
#pragma unroll
  for (int nt = 0; nt < 4; ++nt) {
    int col = n0 + wn * 64 + nt * 16 + c;
    float bv = bias[col];
#pragma unroll
    for (int mt = 0; mt < 4; ++mt) {
      int row = m0 + wm * 64 + mt * 16 + q * 4;
#pragma unroll
      for (int r = 0; r < 4; ++r) Xp[(row + r) * 256 + col] = f2b(acc[mt][nt][r] + bv);
    }
  }
}

// out = Xp @ Wp^T + b_proj, fp32 out (32768 x 256)
__global__ __launch_bounds__(256) void gemm_proj(const u16* __restrict__ Xp,
                                                 const u16* __restrict__ Wp,
                                                 const float* __restrict__ bias,
                                                 float* __restrict__ out) {
  const int m0 = blockIdx.x * 128, n0 = blockIdx.y * 128;
  const int tid = threadIdx.x, lane = tid & 63, wv = tid >> 6;
  const int wm = wv >> 1, wn = wv & 1, q = lane >> 4, c = lane & 15;
  __shared__ short As[8192], Bs[8192];
  f32x4 acc[4][4] = {};
  for (int kb = 0; kb < 256; kb += 64) {
    stage64(Xp, m0, 256, kb, As, tid);
    stage64(Wp, n0, 256, kb, Bs, tid);
    __syncthreads();
    mfma64(As, Bs, wm, wn, lane, acc);
    __syncthreads();
  }
#pragma unroll
  for (int nt = 0; nt < 4; ++nt) {
    int col = n0 + wn * 64 + nt * 16 + c;
    float bv = bias[col];
#pragma unroll
    for (int mt = 0; mt < 4; ++mt) {
      int row = m0 + wm * 64 + mt * 16 + q * 4;
#pragma unroll
      for (int r = 0; r < 4; ++r) out[(row + r) * 256 + col] = acc[mt][nt][r] + bv;
    }
  }
}

// ---------------- stage-1: agents attend keys, aggregate V (unnormalized + atomics) ----------
__global__ __launch_bounds__(256) void s1_attn(const u16* __restrict__ QKV,
                                               const u16* __restrict__ Abf,
                                               float* __restrict__ avac,
                                               float* __restrict__ rsum) {
  const int h = blockIdx.y, n0 = blockIdx.x * 256;
  const int tid = threadIdx.x, lane = tid & 63, wv = tid >> 6;
  const int q = lane >> 4, c = lane & 15;
  extern __shared__ char smem[];
  u16* E  = (u16*)smem;            // [64 agents][264] bf16 (pitch-padded)
  u16* VT = (u16*)(smem + 33792);  // [32 d][264] bf16
  float* RED = (float*)smem;       // overlay after E consumed: [4 waves][2048]

  { // stage V chunk transposed: VT[d][tok_local]
    const u16* vrow = QKV + (n0 + tid) * 768 + 512 + h * 32;
#pragma unroll
    for (int d8 = 0; d8 < 4; ++d8) {
      bf16x8 v = *(const bf16x8*)(vrow + d8 * 8);
#pragma unroll
      for (int e = 0; e < 8; ++e) VT[(d8 * 8 + e) * 264 + tid] = (u16)v[e];
    }
  }
  { // QK^T (M=64 agents, N=64 tokens per wave, K=32) + exp -> E
    bf16x8 af[4], bf[4];
#pragma unroll
    for (int mt = 0; mt < 4; ++mt)
      af[mt] = *(const bf16x8*)(Abf + h * 2048 + (mt * 16 + c) * 32 + q * 8);
#pragma unroll
    for (int nt = 0; nt < 4; ++nt)
      bf[nt] = *(const bf16x8*)(QKV + (n0 + wv * 64 + nt * 16 + c) * 768 + 256 + h * 32 + q * 8);
#pragma unroll
    for (int mt = 0; mt < 4; ++mt)
#pragma unroll
      for (int nt = 0; nt < 4; ++nt) {
        f32x4 s = {0.f, 0.f, 0.f, 0.f};
        s = __builtin_amdgcn_mfma_f32_16x16x32_bf16(af[mt], bf[nt], s, 0, 0, 0);
#pragma unroll
        for (int r = 0; r < 4; ++r) {
          int a = mt * 16 + q * 4 + r, nl = wv * 64 + nt * 16 + c;
          E[a * 264 + nl] = f2b(__expf(s[r]));
        }
      }
  }
  __syncthreads();
  { // row sums of E (denominator partials)
    int a = tid >> 2, seg = tid & 3;
    float sum = 0.f;
    for (int i = 0; i < 64; ++i) sum += b2f(E[a * 264 + seg * 64 + i]);
    sum += __shfl_xor(sum, 1);
    sum += __shfl_xor(sum, 2);
    if (seg == 0) atomicAdd(&rsum[h * 64 + a], sum);
  }
  // PV: each wave reduces its own 64-token K-slab (M=64 agents, N=32 d)
  f32x4 pv[4][2] = {};
#pragma unroll
  for (int ks = 0; ks < 2; ++ks) {
    bf16x8 ap[4], bp[2];
#pragma unroll
    for (int mt = 0; mt < 4; ++mt)
      ap[mt] = *(const bf16x8*)&E[(mt * 16 + c) * 264 + wv * 64 + ks * 32 + q * 8];
#pragma unroll
    for (int nt = 0; nt < 2; ++nt)
      bp[nt] = *(const bf16x8*)&VT[(nt * 16 + c) * 264 + wv * 64 + ks * 32 + q * 8];
#pragma unroll
    for (int mt = 0; mt < 4; ++mt)
#pragma unroll
      for (int nt = 0; nt < 2; ++nt)
        pv[mt][nt] = __builtin_amdgcn_mfma_f32_16x16x32_bf16(ap[mt], bp[nt], pv[mt][nt], 0, 0, 0);
  }
  __syncthreads();            // all E/VT reads done; reuse smem as RED
#pragma unroll
  for (int mt = 0; mt < 4; ++mt)
#pragma unroll
    for (int nt = 0; nt < 2; ++nt)
#pragma unroll
      for (int r = 0; r < 4; ++r)
        RED[wv * 2048 + (mt * 16 + q * 4 + r) * 32 + nt * 16 + c] = pv[mt][nt][r];
  __syncthreads();
  for (int idx = tid; idx < 2048; idx += 256) {
    float t = RED[idx] + RED[2048 + idx] + RED[4096 + idx] + RED[6144 + idx];
    atomicAdd(&avac[h * 2048 + idx], t);
  }
}

// ---------------- stage-2: queries attend agents; scatter-add into Xp ----------------
__global__ __launch_bounds__(256) void s2_attn(const u16* __restrict__ QKV,
                                               const u16* __restrict__ Abf,
                                               const u16* __restrict__ avt,
                                               u16* __restrict__ Xp) {
  const int h = blockIdx.y, n0 = blockIdx.x * 256;
  const int tid = threadIdx.x, lane = tid & 63, wv = tid >> 6;
  const int q = lane >> 4, c = lane & 15;
  extern __shared__ char smem[];
  u16* P = (u16*)smem;      // [256 tok][72] bf16
  float* O = (float*)smem;  // overlay later: [32 d][258] f32

  f32x4 s[4][4];
  { // QK^T: M=64 tokens/wave, N=64 agents, K=32
    bf16x8 af[4], bf[4];
#pragma unroll
    for (int mt = 0; mt < 4; ++mt)
      af[mt] = *(const bf16x8*)(QKV + (n0 + wv * 64 + mt * 16 + c) * 768 + h * 32 + q * 8);
#pragma unroll
    for (int nt = 0; nt < 4; ++nt)
      bf[nt] = *(const bf16x8*)(Abf + h * 2048 + (nt * 16 + c) * 32 + q * 8);
#pragma unroll
    for (int mt = 0; mt < 4; ++mt)
#pragma unroll
      for (int nt = 0; nt < 4; ++nt) {
        f32x4 z = {0.f, 0.f, 0.f, 0.f};
        s[mt][nt] = __builtin_amdgcn_mfma_f32_16x16x32_bf16(af[mt], bf[nt], z, 0, 0, 0);
      }
  }
  // softmax across 64 agents per token row: 4 reg-values + shfl over 16-lane col group
#pragma unroll
  for (int mt = 0; mt < 4; ++mt)
#pragma unroll
    for (int r = 0; r < 4; ++r) {
      float v0 = s[mt][0][r], v1 = s[mt][1][r], v2 = s[mt][2][r], v3 = s[mt][3][r];
      float mx = fmaxf(fmaxf(v0, v1), fmaxf(v2, v3));
      mx = fmaxf(mx, __shfl_xor(mx, 1));
      mx = fmaxf(mx, __shfl_xor(mx, 2));
      mx = fmaxf(mx, __shfl_xor(mx, 4));
      mx = fmaxf(mx, __shfl_xor(mx, 8));
      float e0 = __expf(v0 - mx), e1 = __expf(v1 - mx), e2 = __expf(v2 - mx), e3 = __expf(v3 - mx);
      float sm = e0 + e1 + e2 + e3;
      sm += __shfl_xor(sm, 1);
      sm += __shfl_xor(sm, 2);
      sm += __shfl_xor(sm, 4);
      sm += __shfl_xor(sm, 8);
      float inv = 1.0f / sm;
      int tok = wv * 64 + mt * 16 + q * 4 + r;
      P[tok * 72 +      c] = f2b(e0 * inv);
      P[tok * 72 + 16 + c] = f2b(e1 * inv);
      P[tok * 72 + 32 + c] = f2b(e2 * inv);
      P[tok * 72 + 48 + c] = f2b(e3 * inv);
    }
  __syncthreads();
  // PV: O = P(64x64) @ agent_v(64x32); avt is [h][d][a] (K=a contiguous)
  f32x4 o[4][2] = {};
#pragma unroll
  for (int ks = 0; ks < 2; ++ks) {
    bf16x8 ap[4], bv[2];
#pragma unroll
    for (int mt = 0; mt < 4; ++mt)
      ap[mt] = *(const bf16x8*)&P[(wv * 64 + mt * 16 + c) * 72 + ks * 32 + q * 8];
#pragma unroll
    for (int nt = 0; nt < 2; ++nt)
      bv[nt] = *(const bf16x8*)(avt + h * 2048 + (nt * 16 + c) * 64 + ks * 32 + q * 8);
#pragma unroll
    for (int mt = 0; mt < 4; ++mt)
#pragma unroll
      for (int nt = 0; nt < 2; ++nt)
        o[mt][nt] = __builtin_amdgcn_mfma_f32_16x16x32_bf16(ap[mt], bv[nt], o[mt][nt], 0, 0, 0);
  }
  __syncthreads();  // P reads done; reuse smem as O
#pragma unroll
  for (int mt = 0; mt < 4; ++mt)
#pragma unroll
    for (int nt = 0; nt < 2; ++nt)
#pragma unroll
      for (int r = 0; r < 4; ++r)
        O[(nt * 16 + c) * 258 + wv * 64 + mt * 16 + q * 4 + r] = o[mt][nt][r];
  __syncthreads();
  // coalesced RMW: flat offset (h*32+d)*32768 + n == row-major (n',c') of the torch reshape
  for (int d = 0; d < 32; ++d) {
    int addr = (h * 32 + d) * 32768 + n0 + tid;
    Xp[addr] = f2b(b2f(Xp[addr]) + O[d * 258 + tid]);
  }
}

// ---------------- launch ----------------

extern "C" void kernel_launch(void* const* d_in, const int* in_sizes, int n_in,
                              void* d_out, int out_size, void* d_ws, size_t ws_size,
                              hipStream_t stream) {
  const float* x      = (const float*)d_in[0];
  const float* w_qkv  = (const float*)d_in[1];
  const float* b_qkv  = (const float*)d_in[2];
  const float* w_proj = (const float*)d_in[3];
  const float* b_proj = (const float*)d_in[4];
  const float* w_dwc  = (const float*)d_in[5];
  const float* b_dwc  = (const float*)d_in[6];
  float* out = (float*)d_out;
  char* ws = (char*)d_ws;

  u16* Xb   = (u16*)(ws);              // 16 MB; reused as Xp after QKV GEMM
  u16* QKV  = (u16*)(ws + 16777216);   // 48 MB bf16 (32768 x 768)
  u16* V5   = (u16*)(ws + 67108864);   // 20.1 MB padded volume
  u16* Wc   = (u16*)(ws + 87232512);   // 3.5 MB conv weights [o][t][i]
  u16* Wqb  = (u16*)(ws + 90771456);
  u16* Wpb  = (u16*)(ws + 91164672);
  u16* Abf  = (u16*)(ws + 91295744);   // agents [h][a][d], scale folded
  u16* AVT  = (u16*)(ws + 91328512);   // agent_v^T [h][d][a]
  float* AVAC = (float*)(ws + 91361280);   // 64 KB
  float* RSUM = (float*)(ws + 91426816);   // 2 KB
  float* APRE = (float*)(ws + 91428864);   // 64 KB
  u16* Xp = Xb;

  hipMemsetAsync(AVAC, 0, 65536 + 2048 + 65536, stream);  // AVAC+RSUM+APRE contiguous
  cast_bf16<<<8192, 256, 0, stream>>>(x, Xb, 2097152);
  cast_bf16<<<192, 256, 0, stream>>>(w_qkv, Wqb, 49152);
  cast_bf16<<<64, 256, 0, stream>>>(w_proj, Wpb, 16384);
  pack_wc<<<256, 256, 0, stream>>>(w_dwc, Wc);
  gemm_qkv<<<dim3(256, 6), 256, 0, stream>>>(Xb, Wqb, b_qkv, QKV);
  pool_A<<<512, 256, 0, stream>>>(QKV, APRE);
  pool_fin<<<64, 256, 0, stream>>>(APRE, Abf);
  pad_v<<<4913, 256, 0, stream>>>(QKV, V5);
  s1_attn<<<dim3(128, 8), 256, 50688, stream>>>(QKV, Abf, AVAC, RSUM);
  s1_norm<<<64, 256, 0, stream>>>(AVAC, RSUM, AVT);
  gemm_conv<<<512, 256, 0, stream>>>(V5, Wc, b_dwc, Xp);
  s2_attn<<<dim3(128, 8), 256, 36864, stream>>>(QKV, Abf, AVT, Xp);
  gemm_proj<<<dim3(256, 2), 256, 0, stream>>>(Xp, Wpb, b_proj, out);
}

// Round 4
// 348.640 us; speedup vs baseline: 1.5628x; 1.1689x over previous
//
#include <hip/hip_runtime.h>
#include <stdint.h>

typedef unsigned short u16;
typedef __attribute__((ext_vector_type(8))) short bf16x8;   // 8 bf16 = 4 VGPRs (MFMA A/B frag)
typedef __attribute__((ext_vector_type(4))) float f32x4;    // MFMA C/D frag

__device__ __forceinline__ u16 f2b(float f) {
  unsigned u = __float_as_uint(f);
  unsigned r = (u + 0x7fffu + ((u >> 16) & 1u)) >> 16;  // RNE
  return (u16)r;
}
__device__ __forceinline__ float b2f(u16 s) { return __uint_as_float(((unsigned)s) << 16); }

// async global->LDS, 16B per lane; LDS dest = wave-uniform base + lane*16
__device__ __forceinline__ void async16(const void* g, void* l) {
  __builtin_amdgcn_global_load_lds((const __attribute__((address_space(1))) unsigned int*)g,
                                   (__attribute__((address_space(3))) unsigned int*)l, 16, 0, 0);
}

// ---------------- small prep kernels ----------------

__global__ void cast_bf16(const float* __restrict__ src, u16* __restrict__ dst, int n4) {
  int i = blockIdx.x * 256 + threadIdx.x;
  if (i >= n4) return;
  const float4 v = ((const float4*)src)[i];
  uint2 o;
  o.x = (unsigned)f2b(v.x) | ((unsigned)f2b(v.y) << 16);
  o.y = (unsigned)f2b(v.z) | ((unsigned)f2b(v.w) << 16);
  ((uint2*)dst)[i] = o;
}

// w_dwc[o][i][t] (fp32) -> Wc[o][t][i] bf16, via LDS transpose (coalesced both sides)
__global__ void pack_wc(const float* __restrict__ w, u16* __restrict__ Wc) {
  int o = blockIdx.x;
  __shared__ u16 lds[6912];
  for (int t = threadIdx.x; t < 6912; t += 256) lds[t] = f2b(w[o * 6912 + t]);  // t = i*27+tp
  __syncthreads();
  for (int idx = threadIdx.x; idx < 6912; idx += 256) {
    int tp = idx >> 8, i = idx & 255;
    Wc[o * 6912 + idx] = lds[i * 27 + tp];
  }
}

// agent pooling partials: block (a, slab s of 64 source voxels) -> atomicAdd fp32
__global__ void pool_A(const u16* __restrict__ QKV, float* __restrict__ Apre) {
  int a = blockIdx.x >> 3, s = blockIdx.x & 7;
  int t = threadIdx.x, hp = t >> 5, dp = t & 31;
  int p1 = a >> 4, p2 = (a >> 2) & 3, p3 = a & 3;
  float sum = 0.f;
  for (int ui = 0; ui < 64; ++ui) {
    int u = s * 64 + ui;
    int f1 = p1 * 8 + (u >> 6);
    int f2 = p2 * 8 + ((u >> 3) & 7);
    int f3 = p3 * 8 + (u & 7);
    int vox = f1 * 1024 + f2 * 32 + f3;
    int n  = ((vox & 4095) << 3) + hp;
    int cq = ((vox >> 12) << 5) + dp;
    sum += b2f(QKV[n * 768 + cq]);           // Q region
  }
  atomicAdd(&Apre[(hp * 64 + a) * 32 + dp], sum);
}

__global__ void pool_fin(const float* __restrict__ Apre, u16* __restrict__ Abf) {
  int idx = blockIdx.x * 256 + threadIdx.x;  // 16384
  Abf[idx] = f2b(Apre[idx] * (0.17677669529663687f / 512.0f));
}

// V (QKV cols 512..768) -> padded 34^3 channel-last volume (halo zeroed)
__global__ void pad_v(const u16* __restrict__ QKV, u16* __restrict__ v5) {
  int idx = blockIdx.x * 256 + threadIdx.x;   // 39304*32 = 1257728
  int c8 = idx & 31, vox = idx >> 5;
  int z = vox / 1156, r2 = vox - z * 1156, y = r2 / 34, x = r2 - y * 34;
  bf16x8 val = {0, 0, 0, 0, 0, 0, 0, 0};
  if (z >= 1 && z <= 32 && y >= 1 && y <= 32 && x >= 1 && x <= 32) {
    int n = (z - 1) * 1024 + (y - 1) * 32 + (x - 1);
    val = *(const bf16x8*)(QKV + n * 768 + 512 + c8 * 8);
  }
  *(bf16x8*)(v5 + vox * 256 + c8 * 8) = val;
}

__global__ void s1_norm(const float* __restrict__ avac, const float* __restrict__ rsum,
                        u16* __restrict__ avt) {
  int idx = blockIdx.x * 256 + threadIdx.x;   // 16384
  int h = idx >> 11, rem = idx & 2047, a = rem >> 5, d = rem & 31;
  avt[(h * 32 + d) * 64 + a] = f2b(avac[idx] / rsum[h * 64 + a]);  // transposed for s2 B-frags
}

// ---------------- bf16 NT-GEMM pieces: BK=64 (two 32-K panels), conflict-free LDS --------
// Panel p in {0,1}, group g in [0,8): LDS addr = p*4096 + g*512 + kchunk*128 + row*8
// staged lane-linear (lane = kchunk*16 + row): async16 write and MFMA frag read both
// sequential => zero bank conflicts.

__device__ __forceinline__ void stage64(const u16* src, int row0, int ld, int k0,
                                        short* dst, int tid) {
  int wv = tid >> 6, lane = tid & 63;
  int r15 = lane & 15, kc8 = (lane >> 4) * 8;
#pragma unroll
  for (int j = 0; j < 4; ++j) {
    int p = j & 1, g = wv * 2 + (j >> 1);
    async16(src + (row0 + g * 16 + r15) * ld + k0 + p * 32 + kc8, dst + p * 4096 + g * 512);
  }
}

__device__ __forceinline__ void mfma64(const short* As, const short* Bs, int wm, int wn,
                                       int lane, f32x4 acc[4][4]) {
  const int q = lane >> 4, c = lane & 15;
  const int fo = q * 128 + c * 8;
#pragma unroll
  for (int p = 0; p < 2; ++p) {
    bf16x8 a[4], b[4];
#pragma unroll
    for (int mt = 0; mt < 4; ++mt) a[mt] = *(const bf16x8*)&As[p * 4096 + (wm * 4 + mt) * 512 + fo];
#pragma unroll
    for (int nt = 0; nt < 4; ++nt) b[nt] = *(const bf16x8*)&Bs[p * 4096 + (wn * 4 + nt) * 512 + fo];
#pragma unroll
    for (int mt = 0; mt < 4; ++mt)
#pragma unroll
      for (int nt = 0; nt < 4; ++nt)
        acc[mt][nt] = __builtin_amdgcn_mfma_f32_16x16x32_bf16(a[mt], b[nt], acc[mt][nt], 0, 0, 0);
  }
}

// QKV = Xb @ Wq^T + b, bf16 out (32768 x 768)
__global__ __launch_bounds__(256) void gemm_qkv(const u16* __restrict__ Xb,
                                                const u16* __restrict__ Wq,
                                                const float* __restrict__ bias,
                                                u16* __restrict__ QKV) {
  const int m0 = blockIdx.x * 128, n0 = blockIdx.y * 128;
  const int tid = threadIdx.x, lane = tid & 63, wv = tid >> 6;
  const int wm = wv >> 1, wn = wv & 1, q = lane >> 4, c = lane & 15;
  __shared__ short As[8192], Bs[8192];
  f32x4 acc[4][4] = {};
  for (int kb = 0; kb < 256; kb += 64) {
    stage64(Xb, m0, 256, kb, As, tid);
    stage64(Wq, n0, 256, kb, Bs, tid);
    __syncthreads();
    mfma64(As, Bs, wm, wn, lane, acc);
    __syncthreads();
  }
#pragma unroll
  for (int nt = 0; nt < 4; ++nt) {
    int col = n0 + wn * 64 + nt * 16 + c;
    float bv = bias[col];
#pragma unroll
    for (int mt = 0; mt < 4; ++mt) {
      int row = m0 + wm * 64 + mt * 16 + q * 4;
#pragma unroll
      for (int r = 0; r < 4; ++r) QKV[(row + r) * 768 + col] = f2b(acc[mt][nt][r] + bv);
    }
  }
}

// ---------------- halo-brick implicit-GEMM 3D conv ----------------
// m-tile = 128 voxels = 4 y-rows x 32 x (fixed z). For each (dz,dy): the input slab is
// 136 CONTIGUOUS padded rows of v5 -> staged to LDS once per 32-ch panel; the 3 dx taps
// read LDS with shifted voxel index vx = M + 2*(M>>5) + dx. 72 barrier-steps, 48 MFMA each.
// 1D grid 512, XCD-banded: xcd=bid&7 owns a contiguous band of 32 m-tiles (v5 slab ~2.4MB
// stays L2-resident).
__global__ __launch_bounds__(256) void gemm_conv(const u16* __restrict__ v5,
                                                 const u16* __restrict__ Wc,
                                                 const float* __restrict__ bias,
                                                 u16* __restrict__ Xp) {
  const int bid = blockIdx.x;
  const int xcd = bid & 7, idx = bid >> 3;
  const int n0 = (idx & 1) * 128;
  const int mt_i = xcd * 32 + (idx >> 1);      // m-tile 0..255
  const int m0 = mt_i * 128;
  const int z0 = mt_i >> 3, y0 = (mt_i & 7) * 4;
  const int tid = threadIdx.x, lane = tid & 63, wv = tid >> 6;
  const int wm = wv >> 1, wn = wv & 1, q = lane >> 4, c = lane & 15;
  const int r15 = lane & 15, kq8 = (lane >> 4) * 8;
  __shared__ short As[4608];   // 9 groups * 512 shorts  (A brick slab, 144 rows)
  __shared__ short Bs[12288];  // 3 dx * 8 groups * 512
  f32x4 acc[4][4] = {};
  const u16* browB = Wc + (n0 + r15) * 6912 + kq8;   // + g*16*6912 added per instr
  for (int dzy = 0; dzy < 9; ++dzy) {
    int dz = dzy / 3, dy = dzy - dz * 3;
    int base = (z0 + dz) * 1156 + (y0 + dy) * 34;    // first padded row of the slab
    int tap0 = dzy * 3;
    for (int panel = 0; panel < 8; ++panel) {
      int choff = panel * 32 + kq8;
      for (int g = wv; g < 9; g += 4) {
        int row = base + g * 16 + r15;
        row = row < 39303 ? row : 39303;             // clamp tail (garbage, never read)
        async16(v5 + row * 256 + choff, As + g * 512);
      }
#pragma unroll
      for (int i = wv; i < 24; i += 4) {
        int dx = i >> 3, g = i & 7;
        async16(browB + g * (16 * 6912) + (tap0 + dx) * 256 + panel * 32, Bs + i * 512);
      }
      __syncthreads();
#pragma unroll
      for (int dx = 0; dx < 3; ++dx) {
        bf16x8 a[4], b[4];
#pragma unroll
        for (int mt = 0; mt < 4; ++mt) {
          int M = wm * 64 + mt * 16 + c;
          int vx = M + 2 * (M >> 5) + dx;
          a[mt] = *(const bf16x8*)&As[(vx >> 4) * 512 + q * 128 + (vx & 15) * 8];
        }
#pragma unroll
        for (int nt = 0; nt < 4; ++nt)
          b[nt] = *(const bf16x8*)&Bs[dx * 4096 + (wn * 4 + nt) * 512 + q * 128 + c * 8];
#pragma unroll
        for (int mt = 0; mt < 4; ++mt)
#pragma unroll
          for (int nt = 0; nt < 4; ++nt)
            acc[mt][nt] = __builtin_amdgcn_mfma_f32_16x16x32_bf16(a[mt], b[nt], acc[mt][nt], 0, 0, 0);
      }
      __syncthreads();
    }
  }
#pragma unroll
  for (int nt = 0; nt < 4; ++nt) {
    int col = n0 + wn * 64 + nt * 16 + c;
    float bv = bias[col];
#pragma unroll
    for (int mt = 0; mt < 4; ++mt) {
      int row = m0 + wm * 64 + mt * 16 + q * 4;
#pragma unroll
      for (int r = 0; r < 4; ++r) Xp[(row + r) * 256 + col] = f2b(acc[mt][nt][r] + bv);
    }
  }
}

// out = Xp @ Wp^T + b_proj, fp32 out (32768 x 256)
__global__ __launch_bounds__(256) void gemm_proj(const u16* __restrict__ Xp,
                                                 const u16* __restrict__ Wp,
                                                 const float* __restrict__ bias,
                                                 float* __restrict__ out) {
  const int m0 = blockIdx.x * 128, n0 = blockIdx.y * 128;
  const int tid = threadIdx.x, lane = tid & 63, wv = tid >> 6;
  const int wm = wv >> 1, wn = wv & 1, q = lane >> 4, c = lane & 15;
  __shared__ short As[8192], Bs[8192];
  f32x4 acc[4][4] = {};
  for (int kb = 0; kb < 256; kb += 64) {
    stage64(Xp, m0, 256, kb, As, tid);
    stage64(Wp, n0, 256, kb, Bs, tid);
    __syncthreads();
    mfma64(As, Bs, wm, wn, lane, acc);
    __syncthreads();
  }
#pragma unroll
  for (int nt = 0; nt < 4; ++nt) {
    int col = n0 + wn * 64 + nt * 16 + c;
    float bv = bias[col];
#pragma unroll
    for (int mt = 0; mt < 4; ++mt) {
      int row = m0 + wm * 64 + mt * 16 + q * 4;
#pragma unroll
      for (int r = 0; r < 4; ++r) out[(row + r) * 256 + col] = acc[mt][nt][r] + bv;
    }
  }
}

// ---------------- stage-1: agents attend keys, aggregate V (unnormalized + atomics) ----------
__global__ __launch_bounds__(256) void s1_attn(const u16* __restrict__ QKV,
                                               const u16* __restrict__ Abf,
                                               float* __restrict__ avac,
                                               float* __restrict__ rsum) {
  const int h = blockIdx.y, n0 = blockIdx.x * 256;
  const int tid = threadIdx.x, lane = tid & 63, wv = tid >> 6;
  const int q = lane >> 4, c = lane & 15;
  extern __shared__ char smem[];
  u16* E  = (u16*)smem;            // [64 agents][264] bf16 (pitch-padded)
  u16* VT = (u16*)(smem + 33792);  // [32 d][264] bf16
  float* RED = (float*)smem;       // overlay after E consumed: [4 waves][2048]

  { // stage V chunk transposed: VT[d][tok_local]
    const u16* vrow = QKV + (n0 + tid) * 768 + 512 + h * 32;
#pragma unroll
    for (int d8 = 0; d8 < 4; ++d8) {
      bf16x8 v = *(const bf16x8*)(vrow + d8 * 8);
#pragma unroll
      for (int e = 0; e < 8; ++e) VT[(d8 * 8 + e) * 264 + tid] = (u16)v[e];
    }
  }
  { // QK^T (M=64 agents, N=64 tokens per wave, K=32) + exp -> E
    bf16x8 af[4], bf[4];
#pragma unroll
    for (int mt = 0; mt < 4; ++mt)
      af[mt] = *(const bf16x8*)(Abf + h * 2048 + (mt * 16 + c) * 32 + q * 8);
#pragma unroll
    for (int nt = 0; nt < 4; ++nt)
      bf[nt] = *(const bf16x8*)(QKV + (n0 + wv * 64 + nt * 16 + c) * 768 + 256 + h * 32 + q * 8);
#pragma unroll
    for (int mt = 0; mt < 4; ++mt)
#pragma unroll
      for (int nt = 0; nt < 4; ++nt) {
        f32x4 s = {0.f, 0.f, 0.f, 0.f};
        s = __builtin_amdgcn_mfma_f32_16x16x32_bf16(af[mt], bf[nt], s, 0, 0, 0);
#pragma unroll
        for (int r = 0; r < 4; ++r) {
          int a = mt * 16 + q * 4 + r, nl = wv * 64 + nt * 16 + c;
          E[a * 264 + nl] = f2b(__expf(s[r]));
        }
      }
  }
  __syncthreads();
  { // row sums of E (denominator partials)
    int a = tid >> 2, seg = tid & 3;
    float sum = 0.f;
    for (int i = 0; i < 64; ++i) sum += b2f(E[a * 264 + seg * 64 + i]);
    sum += __shfl_xor(sum, 1);
    sum += __shfl_xor(sum, 2);
    if (seg == 0) atomicAdd(&rsum[h * 64 + a], sum);
  }
  // PV: each wave reduces its own 64-token K-slab (M=64 agents, N=32 d)
  f32x4 pv[4][2] = {};
#pragma unroll
  for (int ks = 0; ks < 2; ++ks) {
    bf16x8 ap[4], bp[2];
#pragma unroll
    for (int mt = 0; mt < 4; ++mt)
      ap[mt] = *(const bf16x8*)&E[(mt * 16 + c) * 264 + wv * 64 + ks * 32 + q * 8];
#pragma unroll
    for (int nt = 0; nt < 2; ++nt)
      bp[nt] = *(const bf16x8*)&VT[(nt * 16 + c) * 264 + wv * 64 + ks * 32 + q * 8];
#pragma unroll
    for (int mt = 0; mt < 4; ++mt)
#pragma unroll
      for (int nt = 0; nt < 2; ++nt)
        pv[mt][nt] = __builtin_amdgcn_mfma_f32_16x16x32_bf16(ap[mt], bp[nt], pv[mt][nt], 0, 0, 0);
  }
  __syncthreads();            // all E/VT reads done; reuse smem as RED
#pragma unroll
  for (int mt = 0; mt < 4; ++mt)
#pragma unroll
    for (int nt = 0; nt < 2; ++nt)
#pragma unroll
      for (int r = 0; r < 4; ++r)
        RED[wv * 2048 + (mt * 16 + q * 4 + r) * 32 + nt * 16 + c] = pv[mt][nt][r];
  __syncthreads();
  for (int idx = tid; idx < 2048; idx += 256) {
    float t = RED[idx] + RED[2048 + idx] + RED[4096 + idx] + RED[6144 + idx];
    atomicAdd(&avac[h * 2048 + idx], t);
  }
}

// ---------------- stage-2: queries attend agents; scatter-add into Xp ----------------
__global__ __launch_bounds__(256) void s2_attn(const u16* __restrict__ QKV,
                                               const u16* __restrict__ Abf,
                                               const u16* __restrict__ avt,
                                               u16* __restrict__ Xp) {
  const int h = blockIdx.y, n0 = blockIdx.x * 256;
  const int tid = threadIdx.x, lane = tid & 63, wv = tid >> 6;
  const int q = lane >> 4, c = lane & 15;
  extern __shared__ char smem[];
  u16* P = (u16*)smem;      // [256 tok][72] bf16
  float* O = (float*)smem;  // overlay later: [32 d][258] f32

  f32x4 s[4][4];
  { // QK^T: M=64 tokens/wave, N=64 agents, K=32
    bf16x8 af[4], bf[4];
#pragma unroll
    for (int mt = 0; mt < 4; ++mt)
      af[mt] = *(const bf16x8*)(QKV + (n0 + wv * 64 + mt * 16 + c) * 768 + h * 32 + q * 8);
#pragma unroll
    for (int nt = 0; nt < 4; ++nt)
      bf[nt] = *(const bf16x8*)(Abf + h * 2048 + (nt * 16 + c) * 32 + q * 8);
#pragma unroll
    for (int mt = 0; mt < 4; ++mt)
#pragma unroll
      for (int nt = 0; nt < 4; ++nt) {
        f32x4 z = {0.f, 0.f, 0.f, 0.f};
        s[mt][nt] = __builtin_amdgcn_mfma_f32_16x16x32_bf16(af[mt], bf[nt], z, 0, 0, 0);
      }
  }
  // softmax across 64 agents per token row: 4 reg-values + shfl over 16-lane col group
#pragma unroll
  for (int mt = 0; mt < 4; ++mt)
#pragma unroll
    for (int r = 0; r < 4; ++r) {
      float v0 = s[mt][0][r], v1 = s[mt][1][r], v2 = s[mt][2][r], v3 = s[mt][3][r];
      float mx = fmaxf(fmaxf(v0, v1), fmaxf(v2, v3));
      mx = fmaxf(mx, __shfl_xor(mx, 1));
      mx = fmaxf(mx, __shfl_xor(mx, 2));
      mx = fmaxf(mx, __shfl_xor(mx, 4));
      mx = fmaxf(mx, __shfl_xor(mx, 8));
      float e0 = __expf(v0 - mx), e1 = __expf(v1 - mx), e2 = __expf(v2 - mx), e3 = __expf(v3 - mx);
      float sm = e0 + e1 + e2 + e3;
      sm += __shfl_xor(sm, 1);
      sm += __shfl_xor(sm, 2);
      sm += __shfl_xor(sm, 4);
      sm += __shfl_xor(sm, 8);
      float inv = 1.0f / sm;
      int tok = wv * 64 + mt * 16 + q * 4 + r;
      P[tok * 72 +      c] = f2b(e0 * inv);
      P[tok * 72 + 16 + c] = f2b(e1 * inv);
      P[tok * 72 + 32 + c] = f2b(e2 * inv);
      P[tok * 72 + 48 + c] = f2b(e3 * inv);
    }
  __syncthreads();
  // PV: O = P(64x64) @ agent_v(64x32); avt is [h][d][a] (K=a contiguous)
  f32x4 o[4][2] = {};
#pragma unroll
  for (int ks = 0; ks < 2; ++ks) {
    bf16x8 ap[4], bv[2];
#pragma unroll
    for (int mt = 0; mt < 4; ++mt)
      ap[mt] = *(const bf16x8*)&P[(wv * 64 + mt * 16 + c) * 72 + ks * 32 + q * 8];
#pragma unroll
    for (int nt = 0; nt < 2; ++nt)
      bv[nt] = *(const bf16x8*)(avt + h * 2048 + (nt * 16 + c) * 64 + ks * 32 + q * 8);
#pragma unroll
    for (int mt = 0; mt < 4; ++mt)
#pragma unroll
      for (int nt = 0; nt < 2; ++nt)
        o[mt][nt] = __builtin_amdgcn_mfma_f32_16x16x32_bf16(ap[mt], bv[nt], o[mt][nt], 0, 0, 0);
  }
  __syncthreads();  // P reads done; reuse smem as O
#pragma unroll
  for (int mt = 0; mt < 4; ++mt)
#pragma unroll
    for (int nt = 0; nt < 2; ++nt)
#pragma unroll
      for (int r = 0; r < 4; ++r)
        O[(nt * 16 + c) * 258 + wv * 64 + mt * 16 + q * 4 + r] = o[mt][nt][r];
  __syncthreads();
  // coalesced RMW: flat offset (h*32+d)*32768 + n == row-major (n',c') of the torch reshape
  for (int d = 0; d < 32; ++d) {
    int addr = (h * 32 + d) * 32768 + n0 + tid;
    Xp[addr] = f2b(b2f(Xp[addr]) + O[d * 258 + tid]);
  }
}

// ---------------- launch ----------------

extern "C" void kernel_launch(void* const* d_in, const int* in_sizes, int n_in,
                              void* d_out, int out_size, void* d_ws, size_t ws_size,
                              hipStream_t stream) {
  const float* x      = (const float*)d_in[0];
  const float* w_qkv  = (const float*)d_in[1];
  const float* b_qkv  = (const float*)d_in[2];
  const float* w_proj = (const float*)d_in[3];
  const float* b_proj = (const float*)d_in[4];
  const float* w_dwc  = (const float*)d_in[5];
  const float* b_dwc  = (const float*)d_in[6];
  float* out = (float*)d_out;
  char* ws = (char*)d_ws;

  u16* Xb   = (u16*)(ws);              // 16 MB; reused as Xp after QKV GEMM
  u16* QKV  = (u16*)(ws + 16777216);   // 48 MB bf16 (32768 x 768)
  u16* V5   = (u16*)(ws + 67108864);   // 20.1 MB padded volume
  u16* Wc   = (u16*)(ws + 87232512);   // 3.5 MB conv weights [o][t][i]
  u16* Wqb  = (u16*)(ws + 90771456);
  u16* Wpb  = (u16*)(ws + 91164672);
  u16* Abf  = (u16*)(ws + 91295744);   // agents [h][a][d], scale folded
  u16* AVT  = (u16*)(ws + 91328512);   // agent_v^T [h][d][a]
  float* AVAC = (float*)(ws + 91361280);   // 64 KB
  float* RSUM = (float*)(ws + 91426816);   // 2 KB
  float* APRE = (float*)(ws + 91428864);   // 64 KB
  u16* Xp = Xb;

  hipMemsetAsync(AVAC, 0, 65536 + 2048 + 65536, stream);  // AVAC+RSUM+APRE contiguous
  cast_bf16<<<8192, 256, 0, stream>>>(x, Xb, 2097152);
  cast_bf16<<<192, 256, 0, stream>>>(w_qkv, Wqb, 49152);
  cast_bf16<<<64, 256, 0, stream>>>(w_proj, Wpb, 16384);
  pack_wc<<<256, 256, 0, stream>>>(w_dwc, Wc);
  gemm_qkv<<<dim3(256, 6), 256, 0, stream>>>(Xb, Wqb, b_qkv, QKV);
  pool_A<<<512, 256, 0, stream>>>(QKV, APRE);
  pool_fin<<<64, 256, 0, stream>>>(APRE, Abf);
  pad_v<<<4913, 256, 0, stream>>>(QKV, V5);
  s1_attn<<<dim3(128, 8), 256, 50688, stream>>>(QKV, Abf, AVAC, RSUM);
  s1_norm<<<64, 256, 0, stream>>>(AVAC, RSUM, AVT);
  gemm_conv<<<512, 256, 0, stream>>>(V5, Wc, b_dwc, Xp);
  s2_attn<<<dim3(128, 8), 256, 36864, stream>>>(QKV, Abf, AVT, Xp);
  gemm_proj<<<dim3(256, 2), 256, 0, stream>>>(Xp, Wpb, b_proj, out);
}